// Round 1
// baseline (728.372 us; speedup 1.0000x reference)
//
#include <hip/hip_runtime.h>

#define NEGV -10000.0f
constexpr int K  = 128;   // states
constexpr int T  = 512;   // timesteps
constexpr int CH = 8;     // h-prefetch chunk (timesteps)

__device__ __forceinline__ void wait_vm0() {
  asm volatile("s_waitcnt vmcnt(0)" ::: "memory");
}
__device__ __forceinline__ void wait_lgkm0() {
  asm volatile("s_waitcnt lgkmcnt(0)" ::: "memory");
}
// async global -> LDS, 16B/lane; LDS dest = wave-uniform base + lane*16
__device__ __forceinline__ void dma16(const float* g, float* l) {
  __builtin_amdgcn_global_load_lds(
      (const __attribute__((address_space(1))) void*)g,
      (__attribute__((address_space(3))) void*)l, 16, 0, 0);
}
__device__ __forceinline__ float readlane1(float v) {
  return __int_as_float(__builtin_amdgcn_readlane(__float_as_int(v), 1));
}

// One block = one batch row = ONE wave (64 lanes). Lane owns TWO adjacent
// states {2l, 2l+1}; their E-rows (exp(trans)) live in 64 named float4
// registers (256 VGPRs). p is exchanged through 512B of LDS: every lane
// reads the FULL p vector as 32 wave-uniform (broadcast, conflict-free)
// ds_read_b128 -> 32KB/step LDS traffic vs 64KB in the 4-wave version,
// and NO s_barrier anywhere (single-wave DS ops are in-order).
// Normalizer tracker = fs(state 2) via v_readlane (lane 1), 1-step stale,
// identical math to the verified Mslot scheme.
__global__ __launch_bounds__(64, 1)
void crf_fwd(const float* __restrict__ h, const float* __restrict__ trans,
             const float* __restrict__ mask, float* __restrict__ out) {
  const int lane = threadIdx.x;    // 0..63
  const int b    = blockIdx.x;
  const int j0   = lane << 1;      // states owned: j0, j0+1

  __shared__ __align__(16) float p_lds[K];           // single buffer (1 wave)
  __shared__ __align__(16) float hbuf[2][CH][K];     // double-buffered h chunks

  const float* hb = h + (size_t)b * T * K;

  // ---- async prefetch h chunk 0 (t=0..7): 4 dma16, each covers 2 rows ----
  #pragma unroll
  for (int q = 0; q < 4; ++q)
    dma16(hb + (size_t)(2 * q + (lane >> 5)) * K + 4 * (lane & 31),
          &hbuf[0][2 * q][0]);

  // ---- len = sum(mask[b,:]) (contiguous prefix of 1s); 8 entries/lane ----
  const float4* m4 = reinterpret_cast<const float4*>(mask + (size_t)b * T + 8 * lane);
  const float4 ma = m4[0], mz = m4[1];
  float msum = ((ma.x + ma.y) + (ma.z + ma.w)) + ((mz.x + mz.y) + (mz.z + mz.w));
  #pragma unroll
  for (int off = 32; off > 0; off >>= 1) msum += __shfl_xor(msum, off);
  const int len = (int)(msum + 0.5f);

  // ---- E rows j0, j0+1 in NAMED float4 registers: exp(trans[j,k]) ----
  const float4* ta4 = reinterpret_cast<const float4*>(trans + (size_t)j0 * K);
  const float4* tb4 = reinterpret_cast<const float4*>(trans + (size_t)(j0 + 1) * K);
#define LDE(n) \
  float4 ea##n = ta4[n], eb##n = tb4[n]; \
  ea##n = make_float4(__expf(ea##n.x), __expf(ea##n.y), __expf(ea##n.z), __expf(ea##n.w)); \
  eb##n = make_float4(__expf(eb##n.x), __expf(eb##n.y), __expf(eb##n.z), __expf(eb##n.w));
  LDE(0)  LDE(1)  LDE(2)  LDE(3)  LDE(4)  LDE(5)  LDE(6)  LDE(7)
  LDE(8)  LDE(9)  LDE(10) LDE(11) LDE(12) LDE(13) LDE(14) LDE(15)
  LDE(16) LDE(17) LDE(18) LDE(19) LDE(20) LDE(21) LDE(22) LDE(23)
  LDE(24) LDE(25) LDE(26) LDE(27) LDE(28) LDE(29) LDE(30) LDE(31)
#undef LDE
  const float2 trE = *reinterpret_cast<const float2*>(trans + K + j0); // trans[EOS=1, j0..j0+1]

  // ---- init: p(0) one-hot at SOS ----
  *reinterpret_cast<float2*>(&p_lds[j0]) = make_float2(j0 == 0 ? 1.0f : 0.0f, 0.0f);
  wait_lgkm0();

  float Scur = 0.0f;   // shift baked into the p we are about to read
  float Strk = 0.0f;   // tracker: fs(state 2) of previous step (1-step stale)
  float fs0 = NEGV, fs1 = NEGV;
  int cur = 0;

  for (int t = 0; t < len; ++t) {
    const int cpos = t & (CH - 1);
    if (cpos == 0) {                 // chunk boundary
      wait_vm0();
      cur = (t >> 3) & 1;
      const int tn = t + CH;
      if (tn < len) {
        #pragma unroll
        for (int q = 0; q < 4; ++q)
          dma16(hb + (size_t)(tn + 2 * q + (lane >> 5)) * K + 4 * (lane & 31),
                &hbuf[cur ^ 1][2 * q][0]);
      }
    }

    const float Snext = Strk;                               // S_{t+1} (stale)
    const float2 hv = *reinterpret_cast<const float2*>(&hbuf[cur][cpos][j0]);

    // full 128-wide dot for BOTH owned states; p reads are broadcast b128
    const float4* p4 = reinterpret_cast<const float4*>(p_lds);
    float a0 = 0.f, a1 = 0.f, a2 = 0.f, a3 = 0.f;
    float c0 = 0.f, c1 = 0.f, c2 = 0.f, c3 = 0.f;
#define DOT(n) { const float4 pv = p4[n]; \
    a0 += ea##n.x * pv.x; a1 += ea##n.y * pv.y; a2 += ea##n.z * pv.z; a3 += ea##n.w * pv.w; \
    c0 += eb##n.x * pv.x; c1 += eb##n.y * pv.y; c2 += eb##n.z * pv.z; c3 += eb##n.w * pv.w; }
    DOT(0)  DOT(1)  DOT(2)  DOT(3)  DOT(4)  DOT(5)  DOT(6)  DOT(7)
    DOT(8)  DOT(9)  DOT(10) DOT(11) DOT(12) DOT(13) DOT(14) DOT(15)
    DOT(16) DOT(17) DOT(18) DOT(19) DOT(20) DOT(21) DOT(22) DOT(23)
    DOT(24) DOT(25) DOT(26) DOT(27) DOT(28) DOT(29) DOT(30) DOT(31)
#undef DOT
    const float tot0 = (a0 + a1) + (a2 + a3);
    const float tot1 = (c0 + c1) + (c2 + c3);

    // off-critical-path factor: g = exp(h + S_t - S_{t+1})
    const float g0 = __expf(hv.x + Scur - Snext);
    const float g1 = __expf(hv.y + Scur - Snext);
    *reinterpret_cast<float2*>(&p_lds[j0]) = make_float2(tot0 * g0, tot1 * g1);

    fs0 = hv.x + Scur + __logf(tot0);                       // true score_{j0}(t)
    fs1 = hv.y + Scur + __logf(tot1);                       // true score_{j0+1}(t)
    Strk = readlane1(fs0);                                  // state j=2 lives in lane 1
    Scur = Snext;
  }

  // ---- epilogue: out[b] = logsumexp_j(fs_j + trans[EOS, j]) ----
  const float f0 = fs0 + trE.x;
  const float f1 = fs1 + trE.y;
  float m = fmaxf(f0, f1);
  #pragma unroll
  for (int off = 32; off > 0; off >>= 1) m = fmaxf(m, __shfl_xor(m, off));
  float e = __expf(f0 - m) + __expf(f1 - m);
  #pragma unroll
  for (int off = 32; off > 0; off >>= 1) e += __shfl_xor(e, off);
  if (lane == 0) out[b] = m + __logf(e);
}

extern "C" void kernel_launch(void* const* d_in, const int* in_sizes, int n_in,
                              void* d_out, int out_size, void* d_ws, size_t ws_size,
                              hipStream_t stream) {
  const float* h     = (const float*)d_in[0];  // (B,T,K) fp32
  const float* trans = (const float*)d_in[1];  // (K,K)   fp32
  const float* mask  = (const float*)d_in[2];  // (B,T)   fp32
  float* out = (float*)d_out;                  // (B,)    fp32
  const int B = in_sizes[0] / (T * K);         // 256
  crf_fwd<<<B, 64, 0, stream>>>(h, trans, mask, out);
}

// Round 3
// 346.584 us; speedup vs baseline: 2.1016x; 2.1016x over previous
//
#include <hip/hip_runtime.h>

#define NEGV -10000.0f
constexpr int K  = 128;   // states
constexpr int T  = 512;   // timesteps
constexpr int CH = 8;     // h-prefetch chunk (timesteps)

// s_barrier WITHOUT the compiler's vmcnt(0) drain.
__device__ __forceinline__ void bar_lgkm() {
  asm volatile("s_waitcnt lgkmcnt(0)\n\ts_barrier" ::: "memory");
}
__device__ __forceinline__ void wait_vm0() {
  asm volatile("s_waitcnt vmcnt(0)" ::: "memory");
}
// async global -> LDS, 16B/lane; LDS dest = wave-uniform base + lane*16
__device__ __forceinline__ void dma16(const float* g, float* l) {
  __builtin_amdgcn_global_load_lds(
      (const __attribute__((address_space(1))) void*)g,
      (__attribute__((address_space(3))) void*)l, 16, 0, 0);
}
// add the quad-mate's value (lanes 2m <-> 2m+1): VALU DPP, no LDS pipe
__device__ __forceinline__ float pair_sum(float x) {
  int o = __builtin_amdgcn_update_dpp(0, __float_as_int(x), 0xB1, 0xF, 0xF, true);
  return x + __int_as_float(o);
}

// One block = one batch row. 256 threads (4 waves); thread = (j = tid>>1,
// half = tid&1); each thread holds HALF an E row (64 floats) in NAMED float4
// registers. KEY CHANGE vs the 286us version: amdgpu_waves_per_eu(1,1).
// Without it, the pre-RA scheduler targets default occupancy, sinks the
// loop-invariant E loads back into the loop (VGPR_Count was 52 -- cannot
// hold 64 E floats), and every step re-fetches 64KB of E from L1/L2
// (~1150 cyc/step, the real bottleneck). Clamping waves/EU to 1 (we run
// exactly 1 block/CU = 4 waves on 4 EUs, so the cap is free) lets the
// allocator keep E resident in registers.
__global__ __attribute__((amdgpu_flat_work_group_size(256, 256),
                          amdgpu_waves_per_eu(1, 1)))
void crf_fwd(const float* __restrict__ h, const float* __restrict__ trans,
             const float* __restrict__ mask, float* __restrict__ out) {
  const int tid  = threadIdx.x;    // 0..255
  const int b    = blockIdx.x;
  const int j    = tid >> 1;       // state owned (each j twice)
  const int half = tid & 1;        // which 64-wide k-slice
  const int wid  = tid >> 6;       // wave id 0..3
  const int lane = tid & 63;

  __shared__ __align__(16) float p_lds[2][K];          // double-buffered p
  __shared__ __align__(16) float hbuf[2][4][CH][32];   // [buf][wave][row][col]
  __shared__ float Mslot[2];                           // tracker, double-buffered
  __shared__ float red[8];

  // ---- len = sum(mask[b,:]) (contiguous prefix of 1s) ----
  float msum = mask[b * T + tid] + mask[b * T + 256 + tid];
  #pragma unroll
  for (int off = 32; off > 0; off >>= 1) msum += __shfl_xor(msum, off);
  if (lane == 0) red[wid] = msum;

  // ---- E half-row in NAMED registers: E[j, 64*half + k], k = 0..63 ----
  const float4* tr4 = reinterpret_cast<const float4*>(trans + j * K + 64 * half);
#define LDE(n) float4 e##n = tr4[n]; \
  e##n = make_float4(__expf(e##n.x), __expf(e##n.y), __expf(e##n.z), __expf(e##n.w));
  LDE(0)  LDE(1)  LDE(2)  LDE(3)  LDE(4)  LDE(5)  LDE(6)  LDE(7)
  LDE(8)  LDE(9)  LDE(10) LDE(11) LDE(12) LDE(13) LDE(14) LDE(15)
#undef LDE
  const float tr_eos = trans[1 * K + j];  // trans[EOS_IDX=1, j]

  // ---- async prefetch of h chunk 0; wave w loads its own j-slice ----
  // hbuf[buf][w][r][c] = h[t0+r, 32w+c]; one dma16/wave/chunk:
  // lane l -> row l>>3, cols 4*(l&7)..+3
  const float* hb = h + (size_t)b * T * K;
  dma16(hb + (size_t)(lane >> 3) * K + 32 * wid + 4 * (lane & 7),
        &hbuf[0][wid][0][0]);

  // ---- init: p(0) one-hot at SOS (both halves write same value) ----
  p_lds[0][j] = (j == 0) ? 1.0f : 0.0f;
  if (tid < 2) Mslot[tid] = 0.0f;
  bar_lgkm();

  const int len = (int)(red[0] + red[1] + red[2] + red[3] + 0.5f);

  float Scur = 0.0f;   // shift that formed the p we are about to read
  float fs   = NEGV;   // true score of state j after the last step
  int   cur  = 0;

  for (int t = 0; t < len; ++t) {
    bar_lgkm();                          // p(t), Mslot writes now visible
    const int cpos = t & (CH - 1);
    const int rpar = t & 1;

    if (cpos == 0) {                     // chunk boundary (own-wave DMA only)
      wait_vm0();
      cur = (t >> 3) & 1;
      const int tn = t + CH;
      if (tn < len) {
        dma16(hb + (size_t)(tn + (lane >> 3)) * K + 32 * wid + 4 * (lane & 7),
              &hbuf[cur ^ 1][wid][0][0]);
      }
    }

    const float Snext = Mslot[rpar ^ 1];               // S_{t+1} (1 step stale)
    const float hv    = hbuf[cur][j >> 5][cpos][j & 31];

    // 64-wide half-dot over k in [64*half, 64*half+64)
    const float4* p4 = reinterpret_cast<const float4*>(p_lds[rpar] + 64 * half);
    float a0 = 0.f, a1 = 0.f, a2 = 0.f, a3 = 0.f;
#define DOT(n) { float4 pv = p4[n]; \
    a0 += e##n.x * pv.x; a1 += e##n.y * pv.y; \
    a2 += e##n.z * pv.z; a3 += e##n.w * pv.w; }
    DOT(0)  DOT(1)  DOT(2)  DOT(3)  DOT(4)  DOT(5)  DOT(6)  DOT(7)
    DOT(8)  DOT(9)  DOT(10) DOT(11) DOT(12) DOT(13) DOT(14) DOT(15)
#undef DOT
    const float tot = pair_sum((a0 + a1) + (a2 + a3));  // full 128-wide dot

    // off-critical-path factor: g = exp(h + S_t - S_{t+1})
    const float g = __expf(hv + Scur - Snext);
    p_lds[rpar ^ 1][j] = tot * g;                       // both halves, same value

    fs = hv + Scur + __logf(tot);                       // true score_j(t)
    if (tid == 4) Mslot[rpar] = fs;                     // tracker = state j=2
    Scur = Snext;
  }

  // ---- epilogue: out[b] = logsumexp_j(fs_j + trans[EOS, j]) ----
  const float f = fs + tr_eos;
  float m = f;
  #pragma unroll
  for (int off = 32; off > 0; off >>= 1) m = fmaxf(m, __shfl_xor(m, off));
  if (lane == 0) red[wid] = m;
  bar_lgkm();
  const float fm = fmaxf(fmaxf(red[0], red[1]), fmaxf(red[2], red[3]));
  float e = (half == 0) ? __expf(f - fm) : 0.0f;        // de-dup the pair copies
  #pragma unroll
  for (int off = 32; off > 0; off >>= 1) e += __shfl_xor(e, off);
  if (lane == 0) red[4 + wid] = e;
  bar_lgkm();
  if (tid == 0) out[b] = fm + __logf((red[4] + red[5]) + (red[6] + red[7]));
}

extern "C" void kernel_launch(void* const* d_in, const int* in_sizes, int n_in,
                              void* d_out, int out_size, void* d_ws, size_t ws_size,
                              hipStream_t stream) {
  const float* h     = (const float*)d_in[0];  // (B,T,K) fp32
  const float* trans = (const float*)d_in[1];  // (K,K)   fp32
  const float* mask  = (const float*)d_in[2];  // (B,T)   fp32
  float* out = (float*)d_out;                  // (B,)    fp32
  const int B = in_sizes[0] / (T * K);         // 256
  crf_fwd<<<B, 256, 0, stream>>>(h, trans, mask, out);
}

// Round 4
// 333.416 us; speedup vs baseline: 2.1846x; 1.0395x over previous
//
#include <hip/hip_runtime.h>

#define NEGV -10000.0f
constexpr int K  = 128;   // states
constexpr int T  = 512;   // timesteps
constexpr int CH = 8;     // h-prefetch chunk (timesteps)

// s_barrier WITHOUT the compiler's vmcnt(0) drain.
__device__ __forceinline__ void bar_lgkm() {
  asm volatile("s_waitcnt lgkmcnt(0)\n\ts_barrier" ::: "memory");
}
__device__ __forceinline__ void wait_vm0() {
  asm volatile("s_waitcnt vmcnt(0)" ::: "memory");
}
// async global -> LDS, 16B/lane; LDS dest = wave-uniform base + lane*16
__device__ __forceinline__ void dma16(const float* g, float* l) {
  __builtin_amdgcn_global_load_lds(
      (const __attribute__((address_space(1))) void*)g,
      (__attribute__((address_space(3))) void*)l, 16, 0, 0);
}
// add the quad-mate's value (lanes 2m <-> 2m+1): VALU DPP, no LDS pipe
__device__ __forceinline__ float pair_sum(float x) {
  int o = __builtin_amdgcn_update_dpp(0, __float_as_int(x), 0xB1, 0xF, 0xF, true);
  return x + __int_as_float(o);
}

// One block = one batch row. NOW 128 threads (2 waves): thread owns TWO
// adjacent states {s0 = 64*wid + 2*(lane>>1), s0+1} over ONE k-half
// (half = tid&1, 64 wide). 128 E floats/thread in NAMED float4 registers
// (VGPR ~190, legal under amdgpu_waves_per_eu(1,1) which R3 proved works:
// VGPR 52->132, E resident). Why: the 286us kernel's bottleneck is the
// per-step serial chain (~1340 cyc), dominated NOT by VALU issue (18%) but
// by 76 LDS instructions/step + a 4-wave barrier turnaround. Two states
// per thread halves p-broadcast register-fill traffic (16K->8K floats) and
// cuts LDS instrs/step to ~36; barrier now syncs 2 waves, not 4. Each
// ds_read_b128 of p now feeds 8 FMAs instead of 4.
__global__ __attribute__((amdgpu_flat_work_group_size(128, 128),
                          amdgpu_waves_per_eu(1, 1)))
void crf_fwd(const float* __restrict__ h, const float* __restrict__ trans,
             const float* __restrict__ mask, float* __restrict__ out) {
  const int tid  = threadIdx.x;    // 0..127
  const int b    = blockIdx.x;
  const int wid  = tid >> 6;       // wave id 0..1
  const int lane = tid & 63;
  const int m    = lane >> 1;      // state-pair index within wave, 0..31
  const int half = tid & 1;        // which 64-wide k-slice
  const int s0   = 64 * wid + 2 * m;  // states owned: s0, s0+1

  __shared__ __align__(16) float p_lds[2][K];          // double-buffered p
  __shared__ __align__(16) float hb3[2][2][CH][64];    // [buf][wave][row][col64]
  __shared__ float Mslot[2];                           // tracker, double-buffered
  __shared__ float red[4];

  // ---- len = sum(mask[b,:]) (contiguous prefix of 1s); 4 floats/thread ----
  const float4 mv = reinterpret_cast<const float4*>(mask + (size_t)b * T)[tid];
  float msum = (mv.x + mv.y) + (mv.z + mv.w);
  #pragma unroll
  for (int off = 32; off > 0; off >>= 1) msum += __shfl_xor(msum, off);
  if (lane == 0) red[wid] = msum;

  // ---- E rows s0, s1 over k-half in NAMED registers (32 float4) ----
  const float4* ta4 = reinterpret_cast<const float4*>(trans + (size_t)s0 * K + 64 * half);
  const float4* tb4 = reinterpret_cast<const float4*>(trans + (size_t)(s0 + 1) * K + 64 * half);
#define LDE(n) \
  float4 ea##n = ta4[n], eb##n = tb4[n]; \
  ea##n = make_float4(__expf(ea##n.x), __expf(ea##n.y), __expf(ea##n.z), __expf(ea##n.w)); \
  eb##n = make_float4(__expf(eb##n.x), __expf(eb##n.y), __expf(eb##n.z), __expf(eb##n.w));
  LDE(0)  LDE(1)  LDE(2)  LDE(3)  LDE(4)  LDE(5)  LDE(6)  LDE(7)
  LDE(8)  LDE(9)  LDE(10) LDE(11) LDE(12) LDE(13) LDE(14) LDE(15)
#undef LDE
  const float2 trE = *reinterpret_cast<const float2*>(trans + K + s0); // trans[EOS=1, s0..s0+1]

  // ---- async prefetch of h chunk 0; wave-PRIVATE slices (own vmcnt!) ----
  // wave w stages cols [64w, 64w+64) of rows t0..t0+7 into hb3[buf][w][*][*].
  // Round r covers rows 4r..4r+3: lane -> row 4r + (lane>>4), col 4*(lane&15).
  const float* hb = h + (size_t)b * T * K;
  #pragma unroll
  for (int r = 0; r < 2; ++r)
    dma16(hb + (size_t)(4 * r + (lane >> 4)) * K + 64 * wid + 4 * (lane & 15),
          &hb3[0][wid][4 * r][0]);

  // ---- init: p(0) one-hot at SOS; tracker = 0 ----
  p_lds[0][tid] = (tid == 0) ? 1.0f : 0.0f;
  if (tid < 2) Mslot[tid] = 0.0f;
  bar_lgkm();

  const int len = (int)(red[0] + red[1] + 0.5f);

  float Scur = 0.0f;   // shift that formed the p we are about to read
  float fs0 = NEGV, fs1 = NEGV;
  int   cur = 0;

  for (int t = 0; t < len; ++t) {
    bar_lgkm();                          // p(t), Mslot writes now visible
    const int cpos = t & (CH - 1);
    const int rpar = t & 1;

    if (cpos == 0) {                     // chunk boundary (own-wave DMA only)
      wait_vm0();
      cur = (t >> 3) & 1;
      const int tn = t + CH;
      if (tn < len) {
        #pragma unroll
        for (int r = 0; r < 2; ++r)
          dma16(hb + (size_t)(tn + 4 * r + (lane >> 4)) * K + 64 * wid + 4 * (lane & 15),
                &hb3[cur ^ 1][wid][4 * r][0]);
      }
    }

    const float Snext = Mslot[rpar ^ 1];               // S_{t+1} (1 step stale)
    const float2 hv = *reinterpret_cast<const float2*>(&hb3[cur][wid][cpos][2 * m]);

    // 64-wide half-dots for BOTH owned states; each b128 feeds 8 FMAs
    const float4* p4 = reinterpret_cast<const float4*>(p_lds[rpar] + 64 * half);
    float a0 = 0.f, a1 = 0.f, a2 = 0.f, a3 = 0.f;
    float c0 = 0.f, c1 = 0.f, c2 = 0.f, c3 = 0.f;
#define DOT(n) { const float4 pv = p4[n]; \
    a0 += ea##n.x * pv.x; a1 += ea##n.y * pv.y; a2 += ea##n.z * pv.z; a3 += ea##n.w * pv.w; \
    c0 += eb##n.x * pv.x; c1 += eb##n.y * pv.y; c2 += eb##n.z * pv.z; c3 += eb##n.w * pv.w; }
    DOT(0)  DOT(1)  DOT(2)  DOT(3)  DOT(4)  DOT(5)  DOT(6)  DOT(7)
    DOT(8)  DOT(9)  DOT(10) DOT(11) DOT(12) DOT(13) DOT(14) DOT(15)
#undef DOT
    const float tot0 = pair_sum((a0 + a1) + (a2 + a3));  // full 128-wide dots
    const float tot1 = pair_sum((c0 + c1) + (c2 + c3));

    // off-critical-path factor: g = exp(h + S_t - S_{t+1}); pair-uniform
    const float g0 = __expf(hv.x + Scur - Snext);
    const float g1 = __expf(hv.y + Scur - Snext);
    *reinterpret_cast<float2*>(&p_lds[rpar ^ 1][s0]) =
        make_float2(tot0 * g0, tot1 * g1);               // both halves, same value

    fs0 = hv.x + Scur + __logf(tot0);                    // true score_{s0}(t)
    fs1 = hv.y + Scur + __logf(tot1);                    // true score_{s0+1}(t)
    if (tid == 2) Mslot[rpar] = fs0;                     // tracker = state j=2
    Scur = Snext;
  }

  // ---- epilogue: out[b] = logsumexp_j(fs_j + trans[EOS, j]) ----
  const float f0 = fs0 + trE.x;
  const float f1 = fs1 + trE.y;
  float mx = fmaxf(f0, f1);
  #pragma unroll
  for (int off = 32; off > 0; off >>= 1) mx = fmaxf(mx, __shfl_xor(mx, off));
  if (lane == 0) red[wid] = mx;
  bar_lgkm();
  const float fm = fmaxf(red[0], red[1]);
  float e = (half == 0) ? (__expf(f0 - fm) + __expf(f1 - fm)) : 0.0f; // de-dup pair
  #pragma unroll
  for (int off = 32; off > 0; off >>= 1) e += __shfl_xor(e, off);
  if (lane == 0) red[2 + wid] = e;
  bar_lgkm();
  if (tid == 0) out[b] = fm + __logf(red[2] + red[3]);
}

extern "C" void kernel_launch(void* const* d_in, const int* in_sizes, int n_in,
                              void* d_out, int out_size, void* d_ws, size_t ws_size,
                              hipStream_t stream) {
  const float* h     = (const float*)d_in[0];  // (B,T,K) fp32
  const float* trans = (const float*)d_in[1];  // (K,K)   fp32
  const float* mask  = (const float*)d_in[2];  // (B,T)   fp32
  float* out = (float*)d_out;                  // (B,)    fp32
  const int B = in_sizes[0] / (T * K);         // 256
  crf_fwd<<<B, 128, 0, stream>>>(h, trans, mask, out);
}